// Round 18
// baseline (268.421 us; speedup 1.0000x reference)
//
#include <hip/hip_runtime.h>
#include <math.h>

#define D_MODEL 1024
#define NHEADS 16
#define HDIM 64
#define BATCH 2
#define SEQ 2048
#define MROWS (BATCH * SEQ)  // 4096

typedef unsigned int uint32;
typedef __attribute__((ext_vector_type(8))) short short8;
typedef __attribute__((ext_vector_type(4))) float f32x4;
typedef __attribute__((ext_vector_type(16))) float f32x16;
typedef __attribute__((ext_vector_type(2))) unsigned int uint2v;

__device__ __forceinline__ unsigned short f2bf(float f) {
  unsigned int u = __float_as_uint(f);
  u += 0x7fffu + ((u >> 16) & 1u);
  return (unsigned short)(u >> 16);
}

__device__ __forceinline__ float fexp2(float x) {
  float r;
  asm("v_exp_f32 %0, %1" : "=v"(r) : "v"(x));
  return r;
}

__device__ __forceinline__ float flog2(float x) {
  float r;
  asm("v_log_f32 %0, %1" : "=v"(r) : "v"(x));
  return r;
}

__device__ __forceinline__ unsigned int cvtpk(float lo, float hi) {
  unsigned int r;
  asm("v_cvt_pk_bf16_f32 %0, %1, %2" : "=v"(r) : "v"(lo), "v"(hi));
  return r;
}

// barrier that waits only on LDS ops (ds_write visibility) — does NOT drain
// the vmcnt store/load queue like __syncthreads does.
__device__ __forceinline__ void bar_lgkm() {
  asm volatile("s_waitcnt lgkmcnt(0)\n\ts_barrier" ::: "memory");
}

__device__ __forceinline__ void gl_lds16(const void* g, void* l) {
  __builtin_amdgcn_global_load_lds((const __attribute__((address_space(1))) void*)g,
                                   (__attribute__((address_space(3))) void*)l, 16, 0, 0);
}

// ---------------------------------------------------------------------------
// Kernel 1: prep — fused activation conversion (blocks 0..6143) and weight
//   transpose+convert (blocks 6144..7167).
// ---------------------------------------------------------------------------
struct PrepArgs {
  const float* act[3];        // query, key, value
  unsigned short* actout[3];  // Xq, Xk, Xv
  const float* w[4];          // Wq, Wk, Wv, Wo
  unsigned short* wout;       // WqT (4 consecutive 2MB slabs)
};

__global__ __launch_bounds__(256) void prep_kernel(PrepArgs args) {
  int bid = blockIdx.x;
  int t = threadIdx.x;
  if (bid < 6144) {
    int z = bid >> 11, blk = bid & 2047;
    const float* s = args.act[z];
    unsigned short* d = args.actout[z];
    int i = (blk * 256 + t) * 8;
    float4 v0 = *(const float4*)(s + i);
    float4 v1 = *(const float4*)(s + i + 4);
    uint4 o;
    o.x = cvtpk(v0.x, v0.y);
    o.y = cvtpk(v0.z, v0.w);
    o.z = cvtpk(v1.x, v1.y);
    o.w = cvtpk(v1.z, v1.w);
    *(uint4*)(d + i) = o;
  } else {
    __shared__ unsigned short tile[64][80];
    int wb = bid - 6144;
    int zz = wb >> 8, rem = wb & 255;
    int n0 = (rem & 15) * 64, k0 = (rem >> 4) * 64;
    const float* W = args.w[zz];
    unsigned short* WT = args.wout + (size_t)zz * (D_MODEL * D_MODEL);
    int r = t >> 2, cc = (t & 3) * 16;
    const float* src = W + (size_t)(k0 + r) * D_MODEL + n0 + cc;
#pragma unroll
    for (int j = 0; j < 16; j += 4) {
      float4 v = *(const float4*)(src + j);
      tile[r][cc + j + 0] = f2bf(v.x);
      tile[r][cc + j + 1] = f2bf(v.y);
      tile[r][cc + j + 2] = f2bf(v.z);
      tile[r][cc + j + 3] = f2bf(v.w);
    }
    __syncthreads();
    __align__(16) unsigned short tmp[16];
#pragma unroll
    for (int j = 0; j < 16; ++j) tmp[j] = tile[cc + j][r];
    unsigned short* d = WT + (size_t)(n0 + r) * D_MODEL + k0 + cc;
    *(uint4*)d = ((uint4*)tmp)[0];
    *(uint4*)(d + 8) = ((uint4*)tmp)[1];
  }
}

// ---------------------------------------------------------------------------
// GEMM body, 128(M)x64(N) tile, BK=64, 4 waves (2x2 over 64x32 each).
// ---------------------------------------------------------------------------
struct GemmArgs {
  const unsigned short* A[3];
  const unsigned short* W[3];
  const float* bias[3];
  void* C[3];
};

#define GEMM_BODY(A_, B_)                                                              \
  for (int kt = 0; kt < D_MODEL; kt += 64) {                                           \
    _Pragma("unroll") for (int i = 0; i < 4; ++i) {                                    \
      int row = wave * 32 + i * 8;                                                     \
      gl_lds16(A_ + (size_t)(m0 + row + r8) * D_MODEL + kt + c8, As + row * 64);       \
    }                                                                                  \
    _Pragma("unroll") for (int i = 0; i < 2; ++i) {                                    \
      int row = wave * 16 + i * 8;                                                     \
      gl_lds16(B_ + (size_t)(n0 + row + r8) * D_MODEL + kt + c8, Bs + row * 64);       \
    }                                                                                  \
    __syncthreads();                                                                   \
    short8 af[4][2], bf[2][2];                                                         \
    _Pragma("unroll") for (int f = 0; f < 4; ++f)                                      \
      _Pragma("unroll") for (int kk = 0; kk < 2; ++kk)                                 \
        af[f][kk] = *(const short8*)((const char*)As + (wm + f * 16 + lr) * 128 +      \
                                     kk * 64 + lg * 16);                               \
    _Pragma("unroll") for (int j = 0; j < 2; ++j)                                      \
      _Pragma("unroll") for (int kk = 0; kk < 2; ++kk)                                 \
        bf[j][kk] = *(const short8*)((const char*)Bs + (wn + j * 16 + lr) * 128 +      \
                                     kk * 64 + lg * 16);                               \
    _Pragma("unroll") for (int i = 0; i < 4; ++i)                                      \
      _Pragma("unroll") for (int j = 0; j < 2; ++j)                                    \
        _Pragma("unroll") for (int kk = 0; kk < 2; ++kk)                               \
          acc[i][j] = __builtin_amdgcn_mfma_f32_16x16x32_bf16(af[i][kk], bf[j][kk],    \
                                                              acc[i][j], 0, 0, 0);     \
    __syncthreads();                                                                   \
  }

// ---------------------------------------------------------------------------
// Kernel 2: QKV GEMM. wgid<1024: C[s][d] = X@W + b for Q,K (z = wgid>>9).
//   wgid>=1024: V TRANSPOSED — A=WvT, B=Xv, C[d][s], bias per row.
// ---------------------------------------------------------------------------
__global__ __launch_bounds__(256) void gemm_qkv_kernel(GemmArgs args) {
  int bid = blockIdx.x;
  int wgid = (bid & 7) * 192 + (bid >> 3);  // 1536 blocks
  const unsigned short *A, *WT;
  const float* bias;
  void* C;
  int m0, n0;
  bool vtrans;
  if (wgid < 1024) {
    int z = wgid >> 9, rem = wgid & 511;
    int x = rem & 15, y = rem >> 4;         // 16 n-tiles, 32 m-tiles
    A = args.A[z]; WT = args.W[z]; bias = args.bias[z]; C = args.C[z];
    n0 = x * 64; m0 = y * 128; vtrans = false;
  } else {
    int rem = wgid - 1024;
    int x2 = rem & 63, y2 = rem >> 6;       // 64 s-tiles, 8 d-tiles
    A = args.W[2];   // WvT  [1024 d][1024 k]
    WT = args.A[2];  // Xv   [4096 s][1024 k]
    bias = args.bias[2]; C = args.C[2];
    n0 = x2 * 64; m0 = y2 * 128; vtrans = true;
  }
  __shared__ __align__(16) unsigned short As[128 * 64];
  __shared__ __align__(16) unsigned short Bs[64 * 64];
  int t = threadIdx.x;
  int wave = t >> 6, lane = t & 63;
  int wm = (wave >> 1) * 64, wn = (wave & 1) * 32;
  int lr = lane & 15, lg = lane >> 4;
  int r8 = lane >> 3, c8 = (lane & 7) * 8;
  f32x4 acc[4][2] = {};

  GEMM_BODY(A, WT)

  if (!vtrans) {
#pragma unroll
    for (int i = 0; i < 4; ++i)
#pragma unroll
      for (int j = 0; j < 2; ++j) {
        int col = n0 + wn + j * 16 + lr;
        float bb = bias[col];
#pragma unroll
        for (int r = 0; r < 4; ++r) {
          int row = m0 + wm + i * 16 + lg * 4 + r;
          ((unsigned short*)C)[(size_t)row * D_MODEL + col] = f2bf(acc[i][j][r] + bb);
        }
      }
  } else {
#pragma unroll
    for (int i = 0; i < 4; ++i)
#pragma unroll
      for (int j = 0; j < 2; ++j) {
        int col = n0 + wn + j * 16 + lr;
#pragma unroll
        for (int r = 0; r < 4; ++r) {
          int row = m0 + wm + i * 16 + lg * 4 + r;  // d index
          ((unsigned short*)C)[(size_t)row * MROWS + col] = f2bf(acc[i][j][r] + bias[row]);
        }
      }
  }
}

// ---------------------------------------------------------------------------
// Kernel 3: attn_ctx — pass A (512 threads, q-tile 256): swapped QK^T +
//   exp2 + lsum + T12 permlane + PV -> ctx; inv spilled to invl_g.
// ---------------------------------------------------------------------------
__global__ __launch_bounds__(512) void attn_ctx_kernel(const unsigned short* Q, const unsigned short* K,
                                                       const unsigned short* Vt2, float* invl_g,
                                                       unsigned short* ctx) {
  int bid = blockIdx.x;                      // 256 blocks
  int wgid = (bid & 7) * 32 + (bid >> 3);    // xcd-chunked remap
  int bh = wgid >> 3;
  int q0 = (wgid & 7) * 256;
  int b = bh >> 4, h = bh & 15;
  int t = threadIdx.x, wave = t >> 6, lane = t & 63;
  int l31 = lane & 31, hi = lane >> 5;

  __shared__ __align__(16) char Ks[2][64 * 128];
  __shared__ __align__(16) char Vs[2][64 * 128];

  const unsigned short* Kp = K + (size_t)(b * SEQ) * D_MODEL + h * HDIM;
  const unsigned short* Vp = Vt2 + (size_t)(h * HDIM) * MROWS + b * SEQ;

  int srow = t >> 3, sch = t & 7;
  int scb = (sch * 16) ^ ((srow & 7) << 4);

  short8 qv[4];
  {
    const unsigned short* qp = Q + (size_t)(b * SEQ + q0 + wave * 32 + l31) * D_MODEL + h * HDIM + hi * 8;
#pragma unroll
    for (int kk = 0; kk < 4; ++kk) qv[kk] = *(const short8*)(qp + kk * 16);
  }

  const float SCL = 0.125f * 1.44269504f;
  float lsum = 0.f;
  f32x16 oacc[2] = {};

  {
    *(uint4*)(Ks[0] + srow * 128 + scb) = *(const uint4*)(Kp + (size_t)srow * D_MODEL + sch * 8);
    *(uint4*)(Vs[0] + srow * 128 + scb) = *(const uint4*)(Vp + (size_t)srow * MROWS + sch * 8);
  }
  bar_lgkm();
  int cur = 0;
  for (int ti = 0; ti < 32; ++ti) {
    uint4 nk, nv;
    bool more = (ti + 1) < 32;
    if (more) {
      nk = *(const uint4*)(Kp + (size_t)((ti + 1) * 64 + srow) * D_MODEL + sch * 8);
      nv = *(const uint4*)(Vp + (size_t)srow * MROWS + (ti + 1) * 64 + sch * 8);
    }
    // QK^T swapped: D[k][q], A = K tile, B = Q^T
    f32x16 st[2] = {};
#pragma unroll
    for (int n = 0; n < 2; ++n)
#pragma unroll
      for (int kk = 0; kk < 4; ++kk) {
        int kr = n * 32 + l31;
        short8 ak = *(const short8*)(Ks[cur] + kr * 128 + ((kk * 32 + hi * 16) ^ ((kr & 7) << 4)));
        st[n] = __builtin_amdgcn_mfma_f32_32x32x16_bf16(ak, qv[kk], st[n], 0, 0, 0);
      }
    // exp2, row-sum, pack to bf16 pairs
    unsigned int P0[2][4], P1[2][4];
#pragma unroll
    for (int n = 0; n < 2; ++n)
#pragma unroll
      for (int j2 = 0; j2 < 4; ++j2) {
        float p0 = fexp2(st[n][4 * j2 + 0] * SCL);
        float p1 = fexp2(st[n][4 * j2 + 1] * SCL);
        float p2 = fexp2(st[n][4 * j2 + 2] * SCL);
        float p3 = fexp2(st[n][4 * j2 + 3] * SCL);
        lsum += (p0 + p1) + (p2 + p3);
        P0[n][j2] = cvtpk(p0, p1);
        P1[n][j2] = cvtpk(p2, p3);
      }
    // permlane32_swap -> A-fragments of P (row = q = lane&31, k contiguous)
    short8 pa[4];
#pragma unroll
    for (int n = 0; n < 2; ++n)
#pragma unroll
      for (int c = 0; c < 2; ++c) {
        uint2v s0 = __builtin_amdgcn_permlane32_swap(P0[n][2 * c], P0[n][2 * c + 1], false, false);
        uint2v s1 = __builtin_amdgcn_permlane32_swap(P1[n][2 * c], P1[n][2 * c + 1], false, false);
        uint4 w;
        w.x = s0.x; w.y = s1.x; w.z = s0.y; w.w = s1.y;
        pa[n * 2 + c] = *(short8*)&w;
      }
    // PV: D[q][dv] += P[q][k] * V[k][dv]
#pragma unroll
    for (int n2 = 0; n2 < 2; ++n2)
#pragma unroll
      for (int kk = 0; kk < 4; ++kk) {
        int vr = n2 * 32 + l31;
        short8 bv = *(const short8*)(Vs[cur] + vr * 128 + ((kk * 32 + hi * 16) ^ ((vr & 7) << 4)));
        oacc[n2] = __builtin_amdgcn_mfma_f32_32x32x16_bf16(pa[kk], bv, oacc[n2], 0, 0, 0);
      }
    if (more) {
      *(uint4*)(Ks[cur ^ 1] + srow * 128 + scb) = nk;
      *(uint4*)(Vs[cur ^ 1] + srow * 128 + scb) = nv;
    }
    bar_lgkm();
    cur ^= 1;
  }
  float tot = lsum + __shfl_xor(lsum, 32, 64);
  float inv = 1.f / tot;
  if (lane < 32) invl_g[(size_t)bh * SEQ + q0 + wave * 32 + l31] = inv;
  float iv16[16];
#pragma unroll
  for (int reg = 0; reg < 16; ++reg) {
    int qr = (reg & 3) + 8 * (reg >> 2) + 4 * hi;
    iv16[reg] = __shfl(inv, qr, 64);
  }
#pragma unroll
  for (int n2 = 0; n2 < 2; ++n2)
#pragma unroll
    for (int reg = 0; reg < 16; ++reg) {
      int qr = (reg & 3) + 8 * (reg >> 2) + 4 * hi;
      int row = b * SEQ + q0 + wave * 32 + qr;
      ctx[(size_t)row * D_MODEL + h * HDIM + n2 * 32 + l31] = f2bf(oacc[n2][reg] * iv16[reg]);
    }
}

// ---------------------------------------------------------------------------
// Kernel 4: FAT — 512 blocks x 512 threads.
//   wgid < 256:  attn_w (pass B): unswapped QK^T + normalized nontemporal
//     fp32 stores; K LDS double-buffered; q-tile 256, 32 tiles/block.
//   wgid >= 256: gemm_o: two independent 128x64 tiles (4 waves each).
//   Independent workloads interleave across CUs: MFMA hides under the
//   537MB store drain.
// ---------------------------------------------------------------------------
__global__ __launch_bounds__(512) void fat_kernel(const unsigned short* Q, const unsigned short* K,
                                                  const float* invl_g, float* attn,
                                                  const unsigned short* Cw, const unsigned short* WoT,
                                                  const float* bias, float* out0) {
  __shared__ __align__(16) char smem[49152];
  int bid = blockIdx.x;                      // 512 blocks
  int wgid = (bid & 7) * 64 + (bid >> 3);    // xcd-chunked remap
  int t = threadIdx.x, wave = t >> 6, lane = t & 63;

  if (wgid < 256) {
    // ==================== attn_w ====================
    int bh = wgid >> 3;
    int q0 = (wgid & 7) * 256;
    int b = bh >> 4, h = bh & 15;
    int l31 = lane & 31, hi = lane >> 5;
    char* Ks0 = smem;
    char* Ks1 = smem + 64 * 128;

    const unsigned short* Kp = K + (size_t)(b * SEQ) * D_MODEL + h * HDIM;
    int srow = t >> 3, sch = t & 7;
    int scb = (sch * 16) ^ ((srow & 7) << 4);

    short8 qv[4];
    {
      const unsigned short* qp = Q + (size_t)(b * SEQ + q0 + wave * 32 + l31) * D_MODEL + h * HDIM + hi * 8;
#pragma unroll
      for (int kk = 0; kk < 4; ++kk) qv[kk] = *(const short8*)(qp + kk * 16);
    }
    const float SCL = 0.125f * 1.44269504f;
    float* rowp[16];
    float l2iv[16];
    {
      float* abase = attn + (size_t)bh * SEQ * SEQ + l31;
      const float* ivb = invl_g + (size_t)bh * SEQ + q0 + wave * 32;
#pragma unroll
      for (int reg = 0; reg < 16; ++reg) {
        int qr = (reg & 3) + 8 * (reg >> 2) + 4 * hi;
        rowp[reg] = abase + (size_t)(q0 + wave * 32 + qr) * SEQ;
        l2iv[reg] = flog2(ivb[qr]);
      }
    }
    {
      *(uint4*)(Ks0 + srow * 128 + scb) = *(const uint4*)(Kp + (size_t)srow * D_MODEL + sch * 8);
    }
    bar_lgkm();
    int cur = 0;
    for (int ti = 0; ti < 32; ++ti) {
      uint4 nk;
      bool more = (ti + 1) < 32;
      if (more) {
        nk = *(const uint4*)(Kp + (size_t)((ti + 1) * 64 + srow) * D_MODEL + sch * 8);
      }
      char* Kc = cur ? Ks1 : Ks0;
      f32x16 st[2] = {};
#pragma unroll
      for (int n = 0; n < 2; ++n)
#pragma unroll
        for (int kk = 0; kk < 4; ++kk) {
          int kr = n * 32 + l31;
          short8 bk = *(const short8*)(Kc + kr * 128 + ((kk * 32 + hi * 16) ^ ((kr & 7) << 4)));
          st[n] = __builtin_amdgcn_mfma_f32_32x32x16_bf16(qv[kk], bk, st[n], 0, 0, 0);
        }
#pragma unroll
      for (int n = 0; n < 2; ++n)
#pragma unroll
        for (int reg = 0; reg < 16; ++reg) {
          float p = fexp2(fmaf(st[n][reg], SCL, l2iv[reg]));
          __builtin_nontemporal_store(p, rowp[reg] + ti * 64 + n * 32);
        }
      if (more) {
        char* Kn = cur ? Ks0 : Ks1;
        *(uint4*)(Kn + srow * 128 + scb) = nk;
      }
      bar_lgkm();
      cur ^= 1;
    }
  } else {
    // ==================== gemm_o: two 128x64 tiles ====================
    int idx = wgid - 256;
    int half = wave >> 2, wave4 = wave & 3;
    int tile_id = idx * 2 + half;
    int x = tile_id & 15, y = tile_id >> 4;
    int n0 = x * 64, m0 = y * 128;
    unsigned short* As = (unsigned short*)(smem + half * 24576);
    unsigned short* Bs = (unsigned short*)(smem + half * 24576 + 16384);
    int wm = (wave4 >> 1) * 64, wn = (wave4 & 1) * 32;
    int lr = lane & 15, lg = lane >> 4;
    int r8 = lane >> 3, c8 = (lane & 7) * 8;
    f32x4 acc[4][2] = {};

    for (int kt = 0; kt < D_MODEL; kt += 64) {
#pragma unroll
      for (int i = 0; i < 4; ++i) {
        int row = wave4 * 32 + i * 8;
        gl_lds16(Cw + (size_t)(m0 + row + r8) * D_MODEL + kt + c8, As + row * 64);
      }
#pragma unroll
      for (int i = 0; i < 2; ++i) {
        int row = wave4 * 16 + i * 8;
        gl_lds16(WoT + (size_t)(n0 + row + r8) * D_MODEL + kt + c8, Bs + row * 64);
      }
      __syncthreads();
      short8 af[4][2], bf[2][2];
#pragma unroll
      for (int f = 0; f < 4; ++f)
#pragma unroll
        for (int kk = 0; kk < 2; ++kk)
          af[f][kk] = *(const short8*)((const char*)As + (wm + f * 16 + lr) * 128 + kk * 64 + lg * 16);
#pragma unroll
      for (int j = 0; j < 2; ++j)
#pragma unroll
        for (int kk = 0; kk < 2; ++kk)
          bf[j][kk] = *(const short8*)((const char*)Bs + (wn + j * 16 + lr) * 128 + kk * 64 + lg * 16);
#pragma unroll
      for (int i = 0; i < 4; ++i)
#pragma unroll
        for (int j = 0; j < 2; ++j)
#pragma unroll
          for (int kk = 0; kk < 2; ++kk)
            acc[i][j] = __builtin_amdgcn_mfma_f32_16x16x32_bf16(af[i][kk], bf[j][kk], acc[i][j], 0, 0, 0);
      __syncthreads();
    }
#pragma unroll
    for (int i = 0; i < 4; ++i)
#pragma unroll
      for (int j = 0; j < 2; ++j) {
        int col = n0 + wn + j * 16 + lr;
        float bb = bias[col];
#pragma unroll
        for (int r = 0; r < 4; ++r) {
          int row = m0 + wm + i * 16 + lg * 4 + r;
          out0[(size_t)row * D_MODEL + col] = acc[i][j][r] + bb;
        }
      }
  }
}

// ---------------------------------------------------------------------------
extern "C" void kernel_launch(void* const* d_in, const int* in_sizes, int n_in,
                              void* d_out, int out_size, void* d_ws, size_t ws_size,
                              hipStream_t stream) {
  const float* query = (const float*)d_in[0];
  const float* key   = (const float*)d_in[1];
  const float* value = (const float*)d_in[2];
  const float* Wq = (const float*)d_in[3];
  const float* bq = (const float*)d_in[4];
  const float* Wk = (const float*)d_in[5];
  const float* bk = (const float*)d_in[6];
  const float* Wv = (const float*)d_in[7];
  const float* bv = (const float*)d_in[8];
  const float* Wo = (const float*)d_in[9];
  const float* bo = (const float*)d_in[10];

  char* ws = (char*)d_ws;
  const size_t MB = (size_t)1 << 20;
  unsigned short* WqT = (unsigned short*)(ws + 0 * MB);   // 4x2MB slabs (WqT..WoT)
  unsigned short* WvT = (unsigned short*)(ws + 4 * MB);
  unsigned short* WoT = (unsigned short*)(ws + 6 * MB);
  unsigned short* Xq  = (unsigned short*)(ws + 8 * MB);
  unsigned short* Xk  = (unsigned short*)(ws + 16 * MB);
  unsigned short* Xv  = (unsigned short*)(ws + 24 * MB);
  unsigned short* Qw  = (unsigned short*)(ws + 32 * MB);
  unsigned short* Kw  = (unsigned short*)(ws + 40 * MB);
  unsigned short* Vt2 = (unsigned short*)(ws + 48 * MB);  // [1024 d][4096 s]
  unsigned short* Cw  = (unsigned short*)(ws + 8 * MB);   // over Xq (dead after QKV gemm)
  float* invl_g       = (float*)(ws + 16 * MB);           // over Xk (dead after QKV gemm)

  float* out0 = (float*)d_out;
  float* attn = out0 + (size_t)MROWS * D_MODEL;

  PrepArgs pa;
  pa.act[0] = query; pa.act[1] = key; pa.act[2] = value;
  pa.actout[0] = Xq; pa.actout[1] = Xk; pa.actout[2] = Xv;
  pa.w[0] = Wq; pa.w[1] = Wk; pa.w[2] = Wv; pa.w[3] = Wo;
  pa.wout = WqT;
  prep_kernel<<<dim3(7168), 256, 0, stream>>>(pa);

  GemmArgs ga;
  ga.A[0] = Xq; ga.A[1] = Xk; ga.A[2] = Xv;
  ga.W[0] = WqT; ga.W[1] = WqT + (size_t)D_MODEL * D_MODEL; ga.W[2] = WvT;
  ga.bias[0] = bq; ga.bias[1] = bk; ga.bias[2] = bv;
  ga.C[0] = Qw; ga.C[1] = Kw; ga.C[2] = Vt2;
  gemm_qkv_kernel<<<dim3(1536), 256, 0, stream>>>(ga);

  attn_ctx_kernel<<<dim3(256), 512, 0, stream>>>(Qw, Kw, Vt2, invl_g, Cw);

  fat_kernel<<<dim3(512), 512, 0, stream>>>(Qw, Kw, invl_g, attn, Cw, WoT, bo, out0);
}

// Round 19
// 248.952 us; speedup vs baseline: 1.0782x; 1.0782x over previous
//
#include <hip/hip_runtime.h>
#include <math.h>

#define D_MODEL 1024
#define NHEADS 16
#define HDIM 64
#define BATCH 2
#define SEQ 2048
#define MROWS (BATCH * SEQ)  // 4096

typedef unsigned int uint32;
typedef __attribute__((ext_vector_type(8))) short short8;
typedef __attribute__((ext_vector_type(4))) float f32x4;
typedef __attribute__((ext_vector_type(16))) float f32x16;
typedef __attribute__((ext_vector_type(2))) unsigned int uint2v;

__device__ __forceinline__ unsigned short f2bf(float f) {
  unsigned int u = __float_as_uint(f);
  u += 0x7fffu + ((u >> 16) & 1u);
  return (unsigned short)(u >> 16);
}

__device__ __forceinline__ float fexp2(float x) {
  float r;
  asm("v_exp_f32 %0, %1" : "=v"(r) : "v"(x));
  return r;
}

__device__ __forceinline__ unsigned int cvtpk(float lo, float hi) {
  unsigned int r;
  asm("v_cvt_pk_bf16_f32 %0, %1, %2" : "=v"(r) : "v"(lo), "v"(hi));
  return r;
}

// barrier that waits only on LDS ops (ds_write visibility) — does NOT drain
// the vmcnt store/load queue like __syncthreads does.
__device__ __forceinline__ void bar_lgkm() {
  asm volatile("s_waitcnt lgkmcnt(0)\n\ts_barrier" ::: "memory");
}

__device__ __forceinline__ void gl_lds16(const void* g, void* l) {
  __builtin_amdgcn_global_load_lds((const __attribute__((address_space(1))) void*)g,
                                   (__attribute__((address_space(3))) void*)l, 16, 0, 0);
}

// ---------------------------------------------------------------------------
// Kernel 1: prep — fused activation conversion (blocks 0..6143) and weight
//   transpose+convert (blocks 6144..7167).
// ---------------------------------------------------------------------------
struct PrepArgs {
  const float* act[3];        // query, key, value
  unsigned short* actout[3];  // Xq, Xk, Xv
  const float* w[4];          // Wq, Wk, Wv, Wo
  unsigned short* wout;       // WqT (4 consecutive 2MB slabs)
};

__global__ __launch_bounds__(256) void prep_kernel(PrepArgs args) {
  int bid = blockIdx.x;
  int t = threadIdx.x;
  if (bid < 6144) {
    int z = bid >> 11, blk = bid & 2047;
    const float* s = args.act[z];
    unsigned short* d = args.actout[z];
    int i = (blk * 256 + t) * 8;
    float4 v0 = *(const float4*)(s + i);
    float4 v1 = *(const float4*)(s + i + 4);
    uint4 o;
    o.x = cvtpk(v0.x, v0.y);
    o.y = cvtpk(v0.z, v0.w);
    o.z = cvtpk(v1.x, v1.y);
    o.w = cvtpk(v1.z, v1.w);
    *(uint4*)(d + i) = o;
  } else {
    __shared__ unsigned short tile[64][80];
    int wb = bid - 6144;
    int zz = wb >> 8, rem = wb & 255;
    int n0 = (rem & 15) * 64, k0 = (rem >> 4) * 64;
    const float* W = args.w[zz];
    unsigned short* WT = args.wout + (size_t)zz * (D_MODEL * D_MODEL);
    int r = t >> 2, cc = (t & 3) * 16;
    const float* src = W + (size_t)(k0 + r) * D_MODEL + n0 + cc;
#pragma unroll
    for (int j = 0; j < 16; j += 4) {
      float4 v = *(const float4*)(src + j);
      tile[r][cc + j + 0] = f2bf(v.x);
      tile[r][cc + j + 1] = f2bf(v.y);
      tile[r][cc + j + 2] = f2bf(v.z);
      tile[r][cc + j + 3] = f2bf(v.w);
    }
    __syncthreads();
    __align__(16) unsigned short tmp[16];
#pragma unroll
    for (int j = 0; j < 16; ++j) tmp[j] = tile[cc + j][r];
    unsigned short* d = WT + (size_t)(n0 + r) * D_MODEL + k0 + cc;
    *(uint4*)d = ((uint4*)tmp)[0];
    *(uint4*)(d + 8) = ((uint4*)tmp)[1];
  }
}

// ---------------------------------------------------------------------------
// GEMM body, 128(M)x64(N) tile, BK=64, 4 waves (2x2 over 64x32 each).
// ---------------------------------------------------------------------------
struct GemmArgs {
  const unsigned short* A[3];
  const unsigned short* W[3];
  const float* bias[3];
  void* C[3];
};

#define GEMM_BODY(A_, B_)                                                              \
  for (int kt = 0; kt < D_MODEL; kt += 64) {                                           \
    _Pragma("unroll") for (int i = 0; i < 4; ++i) {                                    \
      int row = wave * 32 + i * 8;                                                     \
      gl_lds16(A_ + (size_t)(m0 + row + r8) * D_MODEL + kt + c8, As + row * 64);       \
    }                                                                                  \
    _Pragma("unroll") for (int i = 0; i < 2; ++i) {                                    \
      int row = wave * 16 + i * 8;                                                     \
      gl_lds16(B_ + (size_t)(n0 + row + r8) * D_MODEL + kt + c8, Bs + row * 64);       \
    }                                                                                  \
    __syncthreads();                                                                   \
    short8 af[4][2], bf[2][2];                                                         \
    _Pragma("unroll") for (int f = 0; f < 4; ++f)                                      \
      _Pragma("unroll") for (int kk = 0; kk < 2; ++kk)                                 \
        af[f][kk] = *(const short8*)((const char*)As + (wm + f * 16 + lr) * 128 +      \
                                     kk * 64 + lg * 16);                               \
    _Pragma("unroll") for (int j = 0; j < 2; ++j)                                      \
      _Pragma("unroll") for (int kk = 0; kk < 2; ++kk)                                 \
        bf[j][kk] = *(const short8*)((const char*)Bs + (wn + j * 16 + lr) * 128 +      \
                                     kk * 64 + lg * 16);                               \
    _Pragma("unroll") for (int i = 0; i < 4; ++i)                                      \
      _Pragma("unroll") for (int j = 0; j < 2; ++j)                                    \
        _Pragma("unroll") for (int kk = 0; kk < 2; ++kk)                               \
          acc[i][j] = __builtin_amdgcn_mfma_f32_16x16x32_bf16(af[i][kk], bf[j][kk],    \
                                                              acc[i][j], 0, 0, 0);     \
    __syncthreads();                                                                   \
  }

// ---------------------------------------------------------------------------
// Kernel 2: QKV GEMM. wgid<1024: C[s][d] = X@W + b for Q,K (z = wgid>>9).
//   wgid>=1024: V TRANSPOSED — A=WvT, B=Xv, C[d][s], bias per row.
// ---------------------------------------------------------------------------
__global__ __launch_bounds__(256) void gemm_qkv_kernel(GemmArgs args) {
  int bid = blockIdx.x;
  int wgid = (bid & 7) * 192 + (bid >> 3);  // 1536 blocks
  const unsigned short *A, *WT;
  const float* bias;
  void* C;
  int m0, n0;
  bool vtrans;
  if (wgid < 1024) {
    int z = wgid >> 9, rem = wgid & 511;
    int x = rem & 15, y = rem >> 4;         // 16 n-tiles, 32 m-tiles
    A = args.A[z]; WT = args.W[z]; bias = args.bias[z]; C = args.C[z];
    n0 = x * 64; m0 = y * 128; vtrans = false;
  } else {
    int rem = wgid - 1024;
    int x2 = rem & 63, y2 = rem >> 6;       // 64 s-tiles, 8 d-tiles
    A = args.W[2];   // WvT  [1024 d][1024 k]
    WT = args.A[2];  // Xv   [4096 s][1024 k]
    bias = args.bias[2]; C = args.C[2];
    n0 = x2 * 64; m0 = y2 * 128; vtrans = true;
  }
  __shared__ __align__(16) unsigned short As[128 * 64];
  __shared__ __align__(16) unsigned short Bs[64 * 64];
  int t = threadIdx.x;
  int wave = t >> 6, lane = t & 63;
  int wm = (wave >> 1) * 64, wn = (wave & 1) * 32;
  int lr = lane & 15, lg = lane >> 4;
  int r8 = lane >> 3, c8 = (lane & 7) * 8;
  f32x4 acc[4][2] = {};

  GEMM_BODY(A, WT)

  if (!vtrans) {
#pragma unroll
    for (int i = 0; i < 4; ++i)
#pragma unroll
      for (int j = 0; j < 2; ++j) {
        int col = n0 + wn + j * 16 + lr;
        float bb = bias[col];
#pragma unroll
        for (int r = 0; r < 4; ++r) {
          int row = m0 + wm + i * 16 + lg * 4 + r;
          ((unsigned short*)C)[(size_t)row * D_MODEL + col] = f2bf(acc[i][j][r] + bb);
        }
      }
  } else {
#pragma unroll
    for (int i = 0; i < 4; ++i)
#pragma unroll
      for (int j = 0; j < 2; ++j) {
        int col = n0 + wn + j * 16 + lr;
#pragma unroll
        for (int r = 0; r < 4; ++r) {
          int row = m0 + wm + i * 16 + lg * 4 + r;  // d index
          ((unsigned short*)C)[(size_t)row * MROWS + col] = f2bf(acc[i][j][r] + bias[row]);
        }
      }
  }
}

// ---------------------------------------------------------------------------
// Kernel 4: fused attention — 512 threads (8 waves), q-tile 256.
//   Pass A: swapped QK^T (32x32x16) + exp2 + lsum + T12 permlane + PV -> ctx.
//   Pass B: unswapped QK^T recompute (k on lane axis -> coalesced stores) +
//     normalized NONTEMPORAL fp32 stores.
// ---------------------------------------------------------------------------
__global__ __launch_bounds__(512) void attn_kernel(const unsigned short* Q, const unsigned short* K,
                                                   const unsigned short* Vt2, float* attn,
                                                   unsigned short* ctx) {
  int bid = blockIdx.x;                      // 256 blocks
  int wgid = (bid & 7) * 32 + (bid >> 3);    // xcd-chunked remap
  int bh = wgid >> 3;
  int q0 = (wgid & 7) * 256;
  int b = bh >> 4, h = bh & 15;
  int t = threadIdx.x, wave = t >> 6, lane = t & 63;
  int l31 = lane & 31, hi = lane >> 5;

  __shared__ __align__(16) char Ks[2][64 * 128];
  __shared__ __align__(16) char Vs[2][64 * 128];

  const unsigned short* Kp = K + (size_t)(b * SEQ) * D_MODEL + h * HDIM;
  const unsigned short* Vp = Vt2 + (size_t)(h * HDIM) * MROWS + b * SEQ;

  // staging indices: one 16B chunk per thread (512 threads = 64 rows x 8 chunks)
  int srow = t >> 3, sch = t & 7;
  int scb = (sch * 16) ^ ((srow & 7) << 4);

  short8 qv[4];
  {
    const unsigned short* qp = Q + (size_t)(b * SEQ + q0 + wave * 32 + l31) * D_MODEL + h * HDIM + hi * 8;
#pragma unroll
    for (int kk = 0; kk < 4; ++kk) qv[kk] = *(const short8*)(qp + kk * 16);
  }

  const float SCL = 0.125f * 1.44269504f;
  float lsum = 0.f;
  f32x16 oacc[2] = {};

  // ======== pass A ========
  {
    *(uint4*)(Ks[0] + srow * 128 + scb) = *(const uint4*)(Kp + (size_t)srow * D_MODEL + sch * 8);
    *(uint4*)(Vs[0] + srow * 128 + scb) = *(const uint4*)(Vp + (size_t)srow * MROWS + sch * 8);
  }
  bar_lgkm();
  int cur = 0;
  for (int ti = 0; ti < 32; ++ti) {
    uint4 nk, nv;
    bool more = (ti + 1) < 32;
    if (more) {
      nk = *(const uint4*)(Kp + (size_t)((ti + 1) * 64 + srow) * D_MODEL + sch * 8);
      nv = *(const uint4*)(Vp + (size_t)srow * MROWS + (ti + 1) * 64 + sch * 8);
    }
    // QK^T swapped: D[k][q], A = K tile, B = Q^T
    f32x16 st[2] = {};
#pragma unroll
    for (int n = 0; n < 2; ++n)
#pragma unroll
      for (int kk = 0; kk < 4; ++kk) {
        int kr = n * 32 + l31;
        short8 ak = *(const short8*)(Ks[cur] + kr * 128 + ((kk * 32 + hi * 16) ^ ((kr & 7) << 4)));
        st[n] = __builtin_amdgcn_mfma_f32_32x32x16_bf16(ak, qv[kk], st[n], 0, 0, 0);
      }
    // exp2, row-sum, pack to bf16 pairs
    unsigned int P0[2][4], P1[2][4];
#pragma unroll
    for (int n = 0; n < 2; ++n)
#pragma unroll
      for (int j2 = 0; j2 < 4; ++j2) {
        float p0 = fexp2(st[n][4 * j2 + 0] * SCL);
        float p1 = fexp2(st[n][4 * j2 + 1] * SCL);
        float p2 = fexp2(st[n][4 * j2 + 2] * SCL);
        float p3 = fexp2(st[n][4 * j2 + 3] * SCL);
        lsum += (p0 + p1) + (p2 + p3);
        P0[n][j2] = cvtpk(p0, p1);
        P1[n][j2] = cvtpk(p2, p3);
      }
    // permlane32_swap -> A-fragments of P (row = q = lane&31, k contiguous)
    short8 pa[4];
#pragma unroll
    for (int n = 0; n < 2; ++n)
#pragma unroll
      for (int c = 0; c < 2; ++c) {
        uint2v s0 = __builtin_amdgcn_permlane32_swap(P0[n][2 * c], P0[n][2 * c + 1], false, false);
        uint2v s1 = __builtin_amdgcn_permlane32_swap(P1[n][2 * c], P1[n][2 * c + 1], false, false);
        uint4 w;
        w.x = s0.x; w.y = s1.x; w.z = s0.y; w.w = s1.y;
        pa[n * 2 + c] = *(short8*)&w;
      }
    // PV: D[q][dv] += P[q][k] * V[k][dv]
#pragma unroll
    for (int n2 = 0; n2 < 2; ++n2)
#pragma unroll
      for (int kk = 0; kk < 4; ++kk) {
        int vr = n2 * 32 + l31;
        short8 bv = *(const short8*)(Vs[cur] + vr * 128 + ((kk * 32 + hi * 16) ^ ((vr & 7) << 4)));
        oacc[n2] = __builtin_amdgcn_mfma_f32_32x32x16_bf16(pa[kk], bv, oacc[n2], 0, 0, 0);
      }
    if (more) {
      *(uint4*)(Ks[cur ^ 1] + srow * 128 + scb) = nk;
      *(uint4*)(Vs[cur ^ 1] + srow * 128 + scb) = nv;
    }
    bar_lgkm();
    cur ^= 1;
  }
  float tot = lsum + __shfl_xor(lsum, 32, 64);
  float inv = 1.f / tot;
  float iv16[16];
#pragma unroll
  for (int reg = 0; reg < 16; ++reg) {
    int qr = (reg & 3) + 8 * (reg >> 2) + 4 * hi;
    iv16[reg] = __shfl(inv, qr, 64);
  }
#pragma unroll
  for (int n2 = 0; n2 < 2; ++n2)
#pragma unroll
    for (int reg = 0; reg < 16; ++reg) {
      int qr = (reg & 3) + 8 * (reg >> 2) + 4 * hi;
      int row = b * SEQ + q0 + wave * 32 + qr;
      ctx[(size_t)row * D_MODEL + h * HDIM + n2 * 32 + l31] = f2bf(oacc[n2][reg] * iv16[reg]);
    }

  // ======== pass B: recompute + store normalized attention ========
  float* rowp[16];
  {
    float* abase = attn + (size_t)bh * SEQ * SEQ + l31;
#pragma unroll
    for (int reg = 0; reg < 16; ++reg) {
      int qr = (reg & 3) + 8 * (reg >> 2) + 4 * hi;
      rowp[reg] = abase + (size_t)(q0 + wave * 32 + qr) * SEQ;
    }
  }
  {
    *(uint4*)(Ks[0] + srow * 128 + scb) = *(const uint4*)(Kp + (size_t)srow * D_MODEL + sch * 8);
  }
  bar_lgkm();
  cur = 0;
  for (int ti = 0; ti < 32; ++ti) {
    uint4 nk;
    bool more = (ti + 1) < 32;
    if (more) {
      nk = *(const uint4*)(Kp + (size_t)((ti + 1) * 64 + srow) * D_MODEL + sch * 8);
    }
    f32x16 st[2] = {};
#pragma unroll
    for (int n = 0; n < 2; ++n)
#pragma unroll
      for (int kk = 0; kk < 4; ++kk) {
        int kr = n * 32 + l31;
        short8 bk = *(const short8*)(Ks[cur] + kr * 128 + ((kk * 32 + hi * 16) ^ ((kr & 7) << 4)));
        st[n] = __builtin_amdgcn_mfma_f32_32x32x16_bf16(qv[kk], bk, st[n], 0, 0, 0);
      }
#pragma unroll
    for (int n = 0; n < 2; ++n)
#pragma unroll
      for (int reg = 0; reg < 16; ++reg) {
        float p = fexp2(st[n][reg] * SCL) * iv16[reg];
        __builtin_nontemporal_store(p, rowp[reg] + ti * 64 + n * 32);
      }
    if (more) {
      *(uint4*)(Ks[cur ^ 1] + srow * 128 + scb) = nk;
    }
    bar_lgkm();
    cur ^= 1;
  }
}

// ---------------------------------------------------------------------------
// Kernel 5: output projection GEMM, 128x64 tiles -> 512 blocks (2/CU).
// ---------------------------------------------------------------------------
__global__ __launch_bounds__(256) void gemm_o_kernel(const unsigned short* A, const unsigned short* WT,
                                                     const float* bias, float* C) {
  int bid = blockIdx.x;
  int wgid = (bid & 7) * 64 + (bid >> 3);  // 512 blocks
  int x = wgid & 15, y = wgid >> 4;
  int n0 = x * 64, m0 = y * 128;
  __shared__ __align__(16) unsigned short As[128 * 64];
  __shared__ __align__(16) unsigned short Bs[64 * 64];
  int t = threadIdx.x;
  int wave = t >> 6, lane = t & 63;
  int wm = (wave >> 1) * 64, wn = (wave & 1) * 32;
  int lr = lane & 15, lg = lane >> 4;
  int r8 = lane >> 3, c8 = (lane & 7) * 8;
  f32x4 acc[4][2] = {};

  GEMM_BODY(A, WT)

#pragma unroll
  for (int i = 0; i < 4; ++i)
#pragma unroll
    for (int j = 0; j < 2; ++j) {
      int col = n0 + wn + j * 16 + lr;
      float bb = bias[col];
#pragma unroll
      for (int r = 0; r < 4; ++r) {
        int row = m0 + wm + i * 16 + lg * 4 + r;
        C[(size_t)row * D_MODEL + col] = acc[i][j][r] + bb;
      }
    }
}

// ---------------------------------------------------------------------------
extern "C" void kernel_launch(void* const* d_in, const int* in_sizes, int n_in,
                              void* d_out, int out_size, void* d_ws, size_t ws_size,
                              hipStream_t stream) {
  const float* query = (const float*)d_in[0];
  const float* key   = (const float*)d_in[1];
  const float* value = (const float*)d_in[2];
  const float* Wq = (const float*)d_in[3];
  const float* bq = (const float*)d_in[4];
  const float* Wk = (const float*)d_in[5];
  const float* bk = (const float*)d_in[6];
  const float* Wv = (const float*)d_in[7];
  const float* bv = (const float*)d_in[8];
  const float* Wo = (const float*)d_in[9];
  const float* bo = (const float*)d_in[10];

  char* ws = (char*)d_ws;
  const size_t MB = (size_t)1 << 20;
  unsigned short* WqT = (unsigned short*)(ws + 0 * MB);   // 4x2MB slabs (WqT..WoT)
  unsigned short* WvT = (unsigned short*)(ws + 4 * MB);
  unsigned short* WoT = (unsigned short*)(ws + 6 * MB);
  unsigned short* Xq  = (unsigned short*)(ws + 8 * MB);
  unsigned short* Xk  = (unsigned short*)(ws + 16 * MB);
  unsigned short* Xv  = (unsigned short*)(ws + 24 * MB);
  unsigned short* Qw  = (unsigned short*)(ws + 32 * MB);
  unsigned short* Kw  = (unsigned short*)(ws + 40 * MB);
  unsigned short* Vt2 = (unsigned short*)(ws + 48 * MB);  // [1024 d][4096 s]
  unsigned short* Cw  = (unsigned short*)(ws + 8 * MB);   // over Xq (dead after QKV gemm)

  float* out0 = (float*)d_out;
  float* attn = out0 + (size_t)MROWS * D_MODEL;

  PrepArgs pa;
  pa.act[0] = query; pa.act[1] = key; pa.act[2] = value;
  pa.actout[0] = Xq; pa.actout[1] = Xk; pa.actout[2] = Xv;
  pa.w[0] = Wq; pa.w[1] = Wk; pa.w[2] = Wv; pa.w[3] = Wo;
  pa.wout = WqT;
  prep_kernel<<<dim3(7168), 256, 0, stream>>>(pa);

  GemmArgs ga;
  ga.A[0] = Xq; ga.A[1] = Xk; ga.A[2] = Xv;
  ga.W[0] = WqT; ga.W[1] = WqT + (size_t)D_MODEL * D_MODEL; ga.W[2] = WvT;
  ga.bias[0] = bq; ga.bias[1] = bk; ga.bias[2] = bv;
  ga.C[0] = Qw; ga.C[1] = Kw; ga.C[2] = Vt2;
  gemm_qkv_kernel<<<dim3(1536), 256, 0, stream>>>(ga);

  attn_kernel<<<dim3(256), 512, 0, stream>>>(Qw, Kw, Vt2, attn, Cw);

  gemm_o_kernel<<<dim3(512), 256, 0, stream>>>(Cw, WoT, bo, out0);
}